// Round 11
// baseline (330.525 us; speedup 1.0000x reference)
//
#include <hip/hip_runtime.h>

#define NHEAD 8
#define NPAPER 100000
#define NAUTHOR 60000
#define NSUBJ 1000
#define NTOT (NPAPER + NAUTHOR + NSUBJ)
#define NDEG 261000  // author(60000) + paper(100000) + subject(1000) + paper(100000)

typedef __attribute__((ext_vector_type(8))) short bf16x8;
typedef __attribute__((ext_vector_type(4))) float f32x4;

__device__ __forceinline__ unsigned short f2bf(float x) {
    unsigned int u = __builtin_bit_cast(unsigned int, x);
    u += 0x7fffu + ((u >> 16) & 1u);
    return (unsigned short)(u >> 16);
}
__device__ __forceinline__ float bf2f_lo(unsigned int v) {
    return __builtin_bit_cast(float, v << 16);
}
__device__ __forceinline__ float bf2f_hi(unsigned int v) {
    return __builtin_bit_cast(float, v & 0xffff0000u);
}

// ---------------------------------------------------------------------------
// prep (+ deg zero)
// ---------------------------------------------------------------------------
__global__ void prep_kernel(const float* __restrict__ Ws, const float* __restrict__ als,
                            const float* __restrict__ ars,
                            unsigned short* __restrict__ Wt,
                            unsigned short* __restrict__ combo, int* __restrict__ deg) {
    int b = blockIdx.x;
    if (b >= 288) {
        int idx = (b - 288) * 1024 + threadIdx.x * 4;
        if (idx < NDEG) *reinterpret_cast<int4*>(&deg[idx]) = int4{0, 0, 0, 0};
        return;
    }
    int idx = b * 256 + threadIdx.x;
    if (idx < 65536) {
        int r = idx >> 14, rem = idx & 16383, c = rem >> 7, k = rem & 127;
        Wt[idx] = f2bf(Ws[(r << 14) + k * 128 + c]);
    } else if (idx < 65536 + 8192) {
        int j = idx - 65536;
        int r = j >> 11, rem = j & 2047, n = rem >> 7, k = rem & 127;
        int p = r ^ 1;
        const float *W, *a;
        if (n < 8) {
            W = Ws + (r << 14) + k * 128 + n * 16;
            a = als + r * 128 + n * 16;
        } else {
            int h = n - 8;
            W = Ws + (p << 14) + k * 128 + h * 16;
            a = ars + p * 128 + h * 16;
        }
        float s = 0.f;
#pragma unroll
        for (int d = 0; d < 16; ++d) s += W[d] * a[d];
        combo[j] = f2bf(s);
    }
}

// ---------------------------------------------------------------------------
// CSR count
// ---------------------------------------------------------------------------
struct EdgePtrs {
    const int* esrc[4];
    const int* edst[4];
    int ebase[5];
    int nbase[4];
};

__global__ void csr_count(EdgePtrs cp, int* __restrict__ deg) {
    int idx = blockIdx.x * 256 + threadIdx.x;
    if (idx >= cp.ebase[4]) return;
    int r = 0;
    while (idx >= cp.ebase[r + 1]) ++r;
    atomicAdd(&deg[cp.nbase[r] + cp.edst[r][idx - cp.ebase[r]]], 1);
}

// ---------------------------------------------------------------------------
// scan
// ---------------------------------------------------------------------------
__global__ __launch_bounds__(256) void scan_bsum(const int* __restrict__ deg,
                                                 int* __restrict__ bsums, int N) {
    int base = blockIdx.x * 1024 + threadIdx.x * 4;
    int s = 0;
#pragma unroll
    for (int j = 0; j < 4; ++j) {
        int i = base + j;
        if (i < N) s += deg[i];
    }
#pragma unroll
    for (int off = 32; off; off >>= 1) s += __shfl_down(s, off);
    __shared__ int wt[4];
    if ((threadIdx.x & 63) == 0) wt[threadIdx.x >> 6] = s;
    __syncthreads();
    if (threadIdx.x == 0) bsums[blockIdx.x] = wt[0] + wt[1] + wt[2] + wt[3];
}

__global__ __launch_bounds__(256) void scan_final(const int* __restrict__ deg,
                                                  const int* __restrict__ bsums,
                                                  int* __restrict__ row_ptr,
                                                  int* __restrict__ cursor, int N) {
    int t = threadIdx.x;
    __shared__ int s_start;
    __shared__ int wsum[4];
    {
        int acc = 0;
        for (int i = t; i < (int)blockIdx.x; i += 256) acc += bsums[i];
#pragma unroll
        for (int off = 32; off; off >>= 1) acc += __shfl_down(acc, off);
        if ((t & 63) == 0) wsum[t >> 6] = acc;
        __syncthreads();
        if (t == 0) s_start = wsum[0] + wsum[1] + wsum[2] + wsum[3];
        __syncthreads();
    }
    int base = blockIdx.x * 1024 + t * 4;
    int d[4];
    int s = 0;
#pragma unroll
    for (int j = 0; j < 4; ++j) {
        int i = base + j;
        d[j] = (i < N) ? deg[i] : 0;
        s += d[j];
    }
    int inc = s;
#pragma unroll
    for (int off = 1; off < 64; off <<= 1) {
        int u = __shfl_up(inc, off);
        if ((t & 63) >= off) inc += u;
    }
    __shared__ int wt[4];
    if ((t & 63) == 63) wt[t >> 6] = inc;
    __syncthreads();
    int start = s_start;
    for (int w = 0; w < (t >> 6); ++w) start += wt[w];
    start += inc - s;
#pragma unroll
    for (int j = 0; j < 4; ++j) {
        int i = base + j;
        if (i < N) {
            row_ptr[i] = start;
            cursor[i] = start;
        }
        start += d[j];
    }
    if (base < N && base + 4 >= N) row_ptr[N] = start;
}

// ---------------------------------------------------------------------------
// Projection helpers (512 threads, 8 waves, 128 rows/tile)
// ---------------------------------------------------------------------------
__device__ __forceinline__ void stage_W512(unsigned short* Wl,
                                           const unsigned short* __restrict__ Wt,
                                           const unsigned short* __restrict__ cb,
                                           int tid) {
#pragma unroll
    for (int it = 0; it < 5; ++it) {
        int id = it * 512 + tid;
        if (id < 2304) {
            int r = id >> 4, c8 = id & 15;
            const unsigned short* srcp =
                (r < 128) ? (Wt + r * 128) : (cb + (r - 128) * 128);
            uint4 v = *reinterpret_cast<const uint4*>(srcp + c8 * 8);
            *reinterpret_cast<uint4*>(&Wl[(r * 16 + (c8 ^ (r & 15))) * 8]) = v;
        }
    }
}

__device__ __forceinline__ void mfma_set512(const unsigned short* Wl,
                                            unsigned short* Abf, const bf16x8* af,
                                            int tid, int row0, int N,
                                            float* __restrict__ el,
                                            float* __restrict__ er) {
    const int l = tid & 63, w = tid >> 6, lrow = l & 15, lk8 = l >> 4;
#pragma unroll
    for (int t9 = 0; t9 < 9; ++t9) {
        f32x4 acc = f32x4{0.f, 0.f, 0.f, 0.f};
#pragma unroll
        for (int ks = 0; ks < 4; ++ks) {
            int wrow = t9 * 16 + lrow;
            int c8 = ks * 4 + lk8;
            bf16x8 bf = *reinterpret_cast<const bf16x8*>(
                &Wl[(wrow * 16 + (c8 ^ (wrow & 15))) * 8]);
            acc = __builtin_amdgcn_mfma_f32_16x16x32_bf16(af[ks], bf, acc, 0, 0, 0);
        }
        if (t9 < 8) {
#pragma unroll
            for (int r = 0; r < 4; ++r) {
                int rl = w * 16 + lk8 * 4 + r;   // 0..127
                int col = t9 * 16 + lrow;
                Abf[(rl * 16 + ((col >> 3) ^ (rl & 15))) * 8 + (col & 7)] = f2bf(acc[r]);
            }
        } else {
#pragma unroll
            for (int r = 0; r < 4; ++r) {
                int row = row0 + w * 16 + lk8 * 4 + r;
                if (row < N) {
                    if (lrow < 8) el[(size_t)row * 8 + lrow] = acc[r];
                    else er[(size_t)row * 8 + (lrow - 8)] = acc[r];
                }
            }
        }
    }
}

__device__ __forceinline__ void store_hs512(const unsigned short* Abf,
                                            unsigned short* __restrict__ hs, int tid,
                                            int row0, int N) {
#pragma unroll
    for (int it = 0; it < 4; ++it) {
        int id = it * 512 + tid;  // 2048 chunks
        int r = id >> 4, c8 = id & 15;
        int row = row0 + r;
        if (row < N) {
            uint4 v = *reinterpret_cast<const uint4*>(&Abf[(r * 16 + (c8 ^ (r & 15))) * 8]);
            *reinterpret_cast<uint4*>(hs + (size_t)row * 128 + c8 * 8) = v;
        }
    }
}

// ---------------------------------------------------------------------------
// Fused CSR-scatter + persistent pipelined projection.
// Blocks [0, sblk): edge scatter. Blocks [sblk, sblk+pblks): persistent
// projection blocks; grid-stride over tiles with next-tile A prefetched
// into registers so the read stream overlaps MFMA/store phases.
// ---------------------------------------------------------------------------
struct SPArgs {
    const int* esrc[4];
    const int* edst[4];
    int ebase[5];
    int nbase[4];
    int* cursor;
    int* scsr;
    int sblk;
    int ntiles;
    int pstride;
    const float* A[6];
    int N[6];
    int blk0[7];
    const unsigned short* Wt1[6];
    const unsigned short* cb1[6];
    unsigned short* hs1[6];
    float* el1[6];
    float* er1[6];
    const unsigned short* Wt2[6];
    const unsigned short* cb2[6];
    unsigned short* hs2[6];
    float* el2[6];
    float* er2[6];
    int has2[6];
};

__global__ __launch_bounds__(512) void scatter_project(SPArgs a) {
    __shared__ unsigned short Abf[128 * 128];  // 32 KiB
    __shared__ unsigned short Wl[144 * 128];   // 36 KiB
    const int tid = threadIdx.x;
    int bb = blockIdx.x;
    if (bb < a.sblk) {
        int idx = bb * 512 + tid;
        if (idx < a.ebase[4]) {
            int r = 0;
            while (idx >= a.ebase[r + 1]) ++r;
            int e = idx - a.ebase[r];
            int p = atomicAdd(&a.cursor[a.nbase[r] + a.edst[r][e]], 1);
            a.scsr[p] = a.esrc[r][e];
        }
        return;
    }
    bb -= a.sblk;  // persistent projection block id

    f32x4 pf[8];
    auto prefetch = [&](int g) {
        int tt = 0;
        while (g >= a.blk0[tt + 1]) ++tt;
        const float* A = a.A[tt];
        int row0 = (g - a.blk0[tt]) * 128;
        int N = a.N[tt];
#pragma unroll
        for (int it = 0; it < 4; ++it) {
            int id = it * 512 + tid;
            int r = id >> 4, c8 = id & 15;
            int row = row0 + r;
            if (row >= N) row = N - 1;
            const f32x4* ap =
                reinterpret_cast<const f32x4*>(A + (size_t)row * 128 + c8 * 8);
            pf[2 * it] = __builtin_nontemporal_load(ap);
            pf[2 * it + 1] = __builtin_nontemporal_load(ap + 1);
        }
    };

    if (bb < a.ntiles) prefetch(bb);
    for (int g = bb; g < a.ntiles; g += a.pstride) {
        int tt = 0;
        while (g >= a.blk0[tt + 1]) ++tt;
        const int row0 = (g - a.blk0[tt]) * 128;
        const int N = a.N[tt];

        __syncthreads();  // Abf free from previous iteration's stores
        // convert prefetched A -> bf16 swizzled LDS
#pragma unroll
        for (int it = 0; it < 4; ++it) {
            int id = it * 512 + tid;
            int r = id >> 4, c8 = id & 15;
            f32x4 v0 = pf[2 * it], v1 = pf[2 * it + 1];
            uint4 pk;
            pk.x = (unsigned)f2bf(v0.x) | ((unsigned)f2bf(v0.y) << 16);
            pk.y = (unsigned)f2bf(v0.z) | ((unsigned)f2bf(v0.w) << 16);
            pk.z = (unsigned)f2bf(v1.x) | ((unsigned)f2bf(v1.y) << 16);
            pk.w = (unsigned)f2bf(v1.z) | ((unsigned)f2bf(v1.w) << 16);
            *reinterpret_cast<uint4*>(&Abf[(r * 16 + (c8 ^ (r & 15))) * 8]) = pk;
        }
        stage_W512(Wl, a.Wt1[tt], a.cb1[tt], tid);
        __syncthreads();

        const int l = tid & 63, w = tid >> 6, lrow = l & 15, lk8 = l >> 4;
        bf16x8 af[4];
        const int arow = w * 16 + lrow;
#pragma unroll
        for (int ks = 0; ks < 4; ++ks) {
            int c8 = ks * 4 + lk8;
            af[ks] = *reinterpret_cast<const bf16x8*>(
                &Abf[(arow * 16 + (c8 ^ (arow & 15))) * 8]);
        }
        __syncthreads();  // Abf now reusable as D staging

        // issue next tile's loads; they complete under MFMA/store phases
        if (g + a.pstride < a.ntiles) prefetch(g + a.pstride);

        mfma_set512(Wl, Abf, af, tid, row0, N, a.el1[tt], a.er1[tt]);
        __syncthreads();
        store_hs512(Abf, a.hs1[tt], tid, row0, N);
        if (a.has2[tt]) {
            stage_W512(Wl, a.Wt2[tt], a.cb2[tt], tid);  // Wl free after set1 MFMA
            __syncthreads();
            mfma_set512(Wl, Abf, af, tid, row0, N, a.el2[tt], a.er2[tt]);
            __syncthreads();
            store_hs512(Abf, a.hs2[tt], tid, row0, N);
        }
    }
}

// ---------------------------------------------------------------------------
// Dual-input edge-list accumulate (16-lane group, 4-edge unroll)
// ---------------------------------------------------------------------------
__device__ __forceinline__ void acc_dual(
    int p0, int p1, float erd0, float erd1, int l, int h,
    const int* __restrict__ srcs,
    const float* __restrict__ el0, const float* __restrict__ el1,
    const unsigned short* __restrict__ hs0, const unsigned short* __restrict__ hs1,
    float* A0, float* A1, float& DS0, float& DS1) {
    float a0[8], a1[8];
#pragma unroll
    for (int j = 0; j < 8; ++j) { a0[j] = 0.f; a1[j] = 0.f; }
    float d0 = 0.f, d1 = 0.f;
    int p = p0;
    for (; p + 4 <= p1; p += 4) {
        int sx[4];
#pragma unroll
        for (int u = 0; u < 4; ++u) sx[u] = srcs[p + u];
        float ev0[4], ev1[4];
        uint4 q0[4], q1[4];
#pragma unroll
        for (int u = 0; u < 4; ++u) {
            ev0[u] = el0[(size_t)sx[u] * 8 + h] + erd0;
            ev1[u] = el1[(size_t)sx[u] * 8 + h] + erd1;
            q0[u] = *reinterpret_cast<const uint4*>(hs0 + (size_t)sx[u] * 128 + l * 8);
            q1[u] = *reinterpret_cast<const uint4*>(hs1 + (size_t)sx[u] * 128 + l * 8);
        }
#pragma unroll
        for (int u = 0; u < 4; ++u) {
            float e0 = ev0[u];
            e0 = e0 > 0.f ? e0 : 0.2f * e0;
            float ee0 = __expf(e0);
            d0 += ee0;
            a0[0] += ee0 * bf2f_lo(q0[u].x);
            a0[1] += ee0 * bf2f_hi(q0[u].x);
            a0[2] += ee0 * bf2f_lo(q0[u].y);
            a0[3] += ee0 * bf2f_hi(q0[u].y);
            a0[4] += ee0 * bf2f_lo(q0[u].z);
            a0[5] += ee0 * bf2f_hi(q0[u].z);
            a0[6] += ee0 * bf2f_lo(q0[u].w);
            a0[7] += ee0 * bf2f_hi(q0[u].w);
            float e1 = ev1[u];
            e1 = e1 > 0.f ? e1 : 0.2f * e1;
            float ee1 = __expf(e1);
            d1 += ee1;
            a1[0] += ee1 * bf2f_lo(q1[u].x);
            a1[1] += ee1 * bf2f_hi(q1[u].x);
            a1[2] += ee1 * bf2f_lo(q1[u].y);
            a1[3] += ee1 * bf2f_hi(q1[u].y);
            a1[4] += ee1 * bf2f_lo(q1[u].z);
            a1[5] += ee1 * bf2f_hi(q1[u].z);
            a1[6] += ee1 * bf2f_lo(q1[u].w);
            a1[7] += ee1 * bf2f_hi(q1[u].w);
        }
    }
    for (; p < p1; ++p) {
        int s = srcs[p];
        float e0 = el0[(size_t)s * 8 + h] + erd0;
        float e1 = el1[(size_t)s * 8 + h] + erd1;
        uint4 q0 = *reinterpret_cast<const uint4*>(hs0 + (size_t)s * 128 + l * 8);
        uint4 q1 = *reinterpret_cast<const uint4*>(hs1 + (size_t)s * 128 + l * 8);
        e0 = e0 > 0.f ? e0 : 0.2f * e0;
        float ee0 = __expf(e0);
        d0 += ee0;
        a0[0] += ee0 * bf2f_lo(q0.x);
        a0[1] += ee0 * bf2f_hi(q0.x);
        a0[2] += ee0 * bf2f_lo(q0.y);
        a0[3] += ee0 * bf2f_hi(q0.y);
        a0[4] += ee0 * bf2f_lo(q0.z);
        a0[5] += ee0 * bf2f_hi(q0.z);
        a0[6] += ee0 * bf2f_lo(q0.w);
        a0[7] += ee0 * bf2f_hi(q0.w);
        e1 = e1 > 0.f ? e1 : 0.2f * e1;
        float ee1 = __expf(e1);
        d1 += ee1;
        a1[0] += ee1 * bf2f_lo(q1.x);
        a1[1] += ee1 * bf2f_hi(q1.x);
        a1[2] += ee1 * bf2f_lo(q1.y);
        a1[3] += ee1 * bf2f_hi(q1.y);
        a1[4] += ee1 * bf2f_lo(q1.z);
        a1[5] += ee1 * bf2f_hi(q1.z);
        a1[6] += ee1 * bf2f_lo(q1.w);
        a1[7] += ee1 * bf2f_hi(q1.w);
    }
#pragma unroll
    for (int j = 0; j < 8; ++j) { A0[j] = a0[j]; A1[j] = a1[j]; }
    DS0 = d0;
    DS1 = d1;
}

__device__ __forceinline__ void nt_store2(float* op, f32x4 o0, f32x4 o1) {
    f32x4* vp = reinterpret_cast<f32x4*>(op);
    __builtin_nontemporal_store(o0, vp);
    __builtin_nontemporal_store(o1, vp + 1);
}

// ---------------------------------------------------------------------------
// Mega aggregation, dual-input groups.
// ---------------------------------------------------------------------------
#define PB2 6250
#define AB2 3750
#define SB2 1000

struct AggArgs {
    const int* rp;
    const int* srcs;
    const float* el[8];              // [inp*4 + rel]
    const float* er[8];
    const unsigned short* hs[8];
    const float* bs;                 // 4 x 128
    float* out0;
    float* out1;
};

__global__ __launch_bounds__(256) void mega_agg(AggArgs a) {
    int blk = blockIdx.x;
    __shared__ float Am[16][128];
    __shared__ float Dm[16][8];

    if (blk < PB2) {
        int dst = blk * 16 + (threadIdx.x >> 4);
        int l = threadIdx.x & 15, h = l >> 1;
        if (dst >= NPAPER) return;
        float A1_0[8], A1_1[8], d1_0, d1_1;
        acc_dual(a.rp[60000 + dst], a.rp[60000 + dst + 1],
                 a.er[1][(size_t)dst * 8 + h], a.er[5][(size_t)dst * 8 + h], l, h,
                 a.srcs, a.el[1], a.el[5], a.hs[1], a.hs[5], A1_0, A1_1, d1_0, d1_1);
        float A3_0[8], A3_1[8], d3_0, d3_1;
        acc_dual(a.rp[161000 + dst], a.rp[161000 + dst + 1],
                 a.er[3][(size_t)dst * 8 + h], a.er[7][(size_t)dst * 8 + h], l, h,
                 a.srcs, a.el[3], a.el[7], a.hs[3], a.hs[7], A3_0, A3_1, d3_0, d3_1);
        const float4* bp1 = reinterpret_cast<const float4*>(a.bs + 128 + l * 8);
        const float4* bp3 = reinterpret_cast<const float4*>(a.bs + 384 + l * 8);
        float4 b10 = bp1[0], b11 = bp1[1], b30 = bp3[0], b31 = bp3[1];
        float i1 = 1.f / fmaxf(d1_0, 1e-9f);
        float i3 = 1.f / fmaxf(d3_0, 1e-9f);
        f32x4 o0, o1;
        o0.x = 0.5f * ((A1_0[0] * i1 + b10.x) + (A3_0[0] * i3 + b30.x));
        o0.y = 0.5f * ((A1_0[1] * i1 + b10.y) + (A3_0[1] * i3 + b30.y));
        o0.z = 0.5f * ((A1_0[2] * i1 + b10.z) + (A3_0[2] * i3 + b30.z));
        o0.w = 0.5f * ((A1_0[3] * i1 + b10.w) + (A3_0[3] * i3 + b30.w));
        o1.x = 0.5f * ((A1_0[4] * i1 + b11.x) + (A3_0[4] * i3 + b31.x));
        o1.y = 0.5f * ((A1_0[5] * i1 + b11.y) + (A3_0[5] * i3 + b31.y));
        o1.z = 0.5f * ((A1_0[6] * i1 + b11.z) + (A3_0[6] * i3 + b31.z));
        o1.w = 0.5f * ((A1_0[7] * i1 + b11.w) + (A3_0[7] * i3 + b31.w));
        nt_store2(a.out0 + (size_t)dst * 128 + l * 8, o0, o1);
        i1 = 1.f / fmaxf(d1_1, 1e-9f);
        i3 = 1.f / fmaxf(d3_1, 1e-9f);
        o0.x = 0.5f * ((A1_1[0] * i1 + b10.x) + (A3_1[0] * i3 + b30.x));
        o0.y = 0.5f * ((A1_1[1] * i1 + b10.y) + (A3_1[1] * i3 + b30.y));
        o0.z = 0.5f * ((A1_1[2] * i1 + b10.z) + (A3_1[2] * i3 + b30.z));
        o0.w = 0.5f * ((A1_1[3] * i1 + b10.w) + (A3_1[3] * i3 + b30.w));
        o1.x = 0.5f * ((A1_1[4] * i1 + b11.x) + (A3_1[4] * i3 + b31.x));
        o1.y = 0.5f * ((A1_1[5] * i1 + b11.y) + (A3_1[5] * i3 + b31.y));
        o1.z = 0.5f * ((A1_1[6] * i1 + b11.z) + (A3_1[6] * i3 + b31.z));
        o1.w = 0.5f * ((A1_1[7] * i1 + b11.w) + (A3_1[7] * i3 + b31.w));
        nt_store2(a.out1 + (size_t)dst * 128 + l * 8, o0, o1);
    } else if (blk < PB2 + AB2) {
        int dst = (blk - PB2) * 16 + (threadIdx.x >> 4);
        int l = threadIdx.x & 15, h = l >> 1;
        if (dst >= NAUTHOR) return;
        float A0[8], A1[8], d0, d1;
        acc_dual(a.rp[dst], a.rp[dst + 1],
                 a.er[0][(size_t)dst * 8 + h], a.er[4][(size_t)dst * 8 + h], l, h,
                 a.srcs, a.el[0], a.el[4], a.hs[0], a.hs[4], A0, A1, d0, d1);
        const float4* bp = reinterpret_cast<const float4*>(a.bs + l * 8);
        float4 b0 = bp[0], b1 = bp[1];
        float inv = 1.f / fmaxf(d0, 1e-9f);
        f32x4 o0 = {A0[0] * inv + b0.x, A0[1] * inv + b0.y,
                    A0[2] * inv + b0.z, A0[3] * inv + b0.w};
        f32x4 o1 = {A0[4] * inv + b1.x, A0[5] * inv + b1.y,
                    A0[6] * inv + b1.z, A0[7] * inv + b1.w};
        nt_store2(a.out0 + (size_t)(NPAPER + dst) * 128 + l * 8, o0, o1);
        inv = 1.f / fmaxf(d1, 1e-9f);
        o0 = f32x4{A1[0] * inv + b0.x, A1[1] * inv + b0.y,
                   A1[2] * inv + b0.z, A1[3] * inv + b0.w};
        o1 = f32x4{A1[4] * inv + b1.x, A1[5] * inv + b1.y,
                   A1[6] * inv + b1.z, A1[7] * inv + b1.w};
        nt_store2(a.out1 + (size_t)(NPAPER + dst) * 128 + l * 8, o0, o1);
    } else {
        int dst = blk - (PB2 + AB2);
        int gl = threadIdx.x >> 4;
        int inp = gl >> 3, ck = gl & 7;
        int l = threadIdx.x & 15, h = l >> 1;
        const float* el = a.el[inp * 4 + 2];
        const float* er = a.er[inp * 4 + 2];
        const unsigned short* hs = a.hs[inp * 4 + 2];
        int p0 = a.rp[160000 + dst], p1 = a.rp[160000 + dst + 1];
        float erd = er[(size_t)dst * 8 + h];
        float acc8[8];
#pragma unroll
        for (int j = 0; j < 8; ++j) acc8[j] = 0.f;
        float dsum = 0.f;
        for (int p = p0 + ck; p < p1; p += 8) {
            int s = a.srcs[p];
            float e = el[(size_t)s * 8 + h] + erd;
            e = e > 0.f ? e : 0.2f * e;
            float ee = __expf(e);
            uint4 q = *reinterpret_cast<const uint4*>(hs + (size_t)s * 128 + l * 8);
            dsum += ee;
            acc8[0] += ee * bf2f_lo(q.x);
            acc8[1] += ee * bf2f_hi(q.x);
            acc8[2] += ee * bf2f_lo(q.y);
            acc8[3] += ee * bf2f_hi(q.y);
            acc8[4] += ee * bf2f_lo(q.z);
            acc8[5] += ee * bf2f_hi(q.z);
            acc8[6] += ee * bf2f_lo(q.w);
            acc8[7] += ee * bf2f_hi(q.w);
        }
#pragma unroll
        for (int j = 0; j < 8; ++j) Am[gl][l * 8 + j] = acc8[j];
        if ((l & 1) == 0) Dm[gl][h] = dsum;
        __syncthreads();
        int c = threadIdx.x;
        int ci = c >> 7;
        int col = c & 127;
        float s = 0.f, dn = 0.f;
        int hh = col >> 4;
#pragma unroll
        for (int g = 0; g < 8; ++g) {
            s += Am[ci * 8 + g][col];
            dn += Dm[ci * 8 + g][hh];
        }
        float v = s / fmaxf(dn, 1e-9f) + a.bs[256 + col];
        float* outp = (ci ? a.out1 : a.out0) + (size_t)(NPAPER + NAUTHOR + dst) * 128 + col;
        __builtin_nontemporal_store(v, outp);
    }
}

// ---------------------------------------------------------------------------
extern "C" void kernel_launch(void* const* d_in, const int* in_sizes, int n_in,
                              void* d_out, int out_size, void* d_ws, size_t ws_size,
                              hipStream_t stream) {
    const float* Ws4 = (const float*)d_in[14];
    const float* als = (const float*)d_in[15];
    const float* ars = (const float*)d_in[16];
    const float* bs = (const float*)d_in[17];
    float* out = (float*)d_out;

    const int Es[4] = {in_sizes[6], in_sizes[8], in_sizes[10], in_sizes[12]};
    const int Nsrcs[4] = {NPAPER, NAUTHOR, NPAPER, NSUBJ};
    const int Ndsts[4] = {NAUTHOR, NPAPER, NSUBJ, NPAPER};
    const int Etot = Es[0] + Es[1] + Es[2] + Es[3];

    char* wsp = (char*)d_ws;
    auto carve = [&](size_t bytes) {
        char* p = wsp;
        wsp += (bytes + 255) & ~(size_t)255;
        return p;
    };
    unsigned short* Wt = (unsigned short*)carve(4 * 16384 * 2);
    unsigned short* combo = (unsigned short*)carve(4 * 2048 * 2);
    unsigned short* hsb[2][4];
    float* elb[2][4];
    float* erb[2][4];
    for (int i = 0; i < 2; ++i)
        for (int r = 0; r < 4; ++r) {
            hsb[i][r] = (unsigned short*)carve((size_t)Nsrcs[r] * 128 * 2);
            elb[i][r] = (float*)carve((size_t)Nsrcs[r] * 8 * 4);
            erb[i][r] = (float*)carve((size_t)Ndsts[r] * 8 * 4);
        }
    int* deg = (int*)carve((size_t)NDEG * 4);
    int* cursor = (int*)carve((size_t)NDEG * 4);
    int* bsums = (int*)carve(1024);
    int* rp = (int*)carve((size_t)(NDEG + 1) * 4);
    int* scsr = (int*)carve((size_t)Etot * 4);

    EdgePtrs ep;
    ep.esrc[0] = (const int*)d_in[6];  ep.edst[0] = (const int*)d_in[7];
    ep.esrc[1] = (const int*)d_in[8];  ep.edst[1] = (const int*)d_in[9];
    ep.esrc[2] = (const int*)d_in[10]; ep.edst[2] = (const int*)d_in[11];
    ep.esrc[3] = (const int*)d_in[12]; ep.edst[3] = (const int*)d_in[13];
    ep.ebase[0] = 0;
    for (int r = 0; r < 4; ++r) ep.ebase[r + 1] = ep.ebase[r] + Es[r];
    ep.nbase[0] = 0;
    ep.nbase[1] = 60000;
    ep.nbase[2] = 160000;
    ep.nbase[3] = 161000;

    // 1. prep (Wt/combo) + deg zero
    prep_kernel<<<288 + (NDEG + 1023) / 1024, 256, 0, stream>>>(Ws4, als, ars, Wt,
                                                                combo, deg);
    // 2. count
    csr_count<<<(Etot + 255) / 256, 256, 0, stream>>>(ep, deg);
    // 3-4. scan
    int nb = (NDEG + 1023) / 1024;  // 255
    scan_bsum<<<nb, 256, 0, stream>>>(deg, bsums, NDEG);
    scan_final<<<nb, 256, 0, stream>>>(deg, bsums, rp, cursor, NDEG);

    // 5. scatter + persistent pipelined projection
    SPArgs sp;
    for (int r = 0; r < 4; ++r) {
        sp.esrc[r] = ep.esrc[r];
        sp.edst[r] = ep.edst[r];
        sp.nbase[r] = ep.nbase[r];
    }
    for (int r = 0; r < 5; ++r) sp.ebase[r] = ep.ebase[r];
    sp.cursor = cursor;
    sp.scsr = scsr;
    sp.sblk = (Etot + 511) / 512;

    int blk = 0;
    for (int ti = 0; ti < 6; ++ti) {
        int i = ti & 1;
        int nodeT = ti >> 1;  // 0 paper, 1 author, 2 subject
        const int relOf[3] = {0, 1, 3};
        int r = relOf[nodeT];
        const float* feats[3] = {(const float*)d_in[0 + 3 * i],
                                 (const float*)d_in[1 + 3 * i],
                                 (const float*)d_in[2 + 3 * i]};
        sp.A[ti] = feats[nodeT];
        sp.N[ti] = (nodeT == 0) ? NPAPER : (nodeT == 1 ? NAUTHOR : NSUBJ);
        sp.blk0[ti] = blk;
        blk += (sp.N[ti] + 127) / 128;
        sp.Wt1[ti] = Wt + (size_t)r * 16384;
        sp.cb1[ti] = combo + (size_t)r * 2048;
        sp.hs1[ti] = hsb[i][r];
        sp.el1[ti] = elb[i][r];
        sp.er1[ti] = erb[i][r ^ 1];
        sp.has2[ti] = (nodeT == 0);
        int r2 = 2;
        sp.Wt2[ti] = Wt + (size_t)r2 * 16384;
        sp.cb2[ti] = combo + (size_t)r2 * 2048;
        sp.hs2[ti] = hsb[i][r2];
        sp.el2[ti] = elb[i][r2];
        sp.er2[ti] = erb[i][r2 ^ 1];
    }
    sp.blk0[6] = blk;
    sp.ntiles = blk;
    int pblks = blk < 512 ? blk : 512;
    sp.pstride = pblks;
    scatter_project<<<sp.sblk + pblks, 512, 0, stream>>>(sp);

    // 6. mega aggregation (dual-input groups)
    AggArgs ag;
    ag.rp = rp;
    ag.srcs = scsr;
    for (int i = 0; i < 2; ++i)
        for (int r = 0; r < 4; ++r) {
            ag.el[i * 4 + r] = elb[i][r];
            ag.er[i * 4 + r] = erb[i][r];
            ag.hs[i * 4 + r] = hsb[i][r];
        }
    ag.bs = bs;
    ag.out0 = out;
    ag.out1 = out + (size_t)NTOT * 128;
    mega_agg<<<PB2 + AB2 + SB2, 256, 0, stream>>>(ag);
}

// Round 12
// 325.768 us; speedup vs baseline: 1.0146x; 1.0146x over previous
//
#include <hip/hip_runtime.h>

#define NHEAD 8
#define NPAPER 100000
#define NAUTHOR 60000
#define NSUBJ 1000
#define NTOT (NPAPER + NAUTHOR + NSUBJ)
#define NDEG 261000  // author(60000) + paper(100000) + subject(1000) + paper(100000)

typedef __attribute__((ext_vector_type(8))) short bf16x8;
typedef __attribute__((ext_vector_type(4))) float f32x4;

__device__ __forceinline__ unsigned short f2bf(float x) {
    unsigned int u = __builtin_bit_cast(unsigned int, x);
    u += 0x7fffu + ((u >> 16) & 1u);
    return (unsigned short)(u >> 16);
}
__device__ __forceinline__ float bf2f_lo(unsigned int v) {
    return __builtin_bit_cast(float, v << 16);
}
__device__ __forceinline__ float bf2f_hi(unsigned int v) {
    return __builtin_bit_cast(float, v & 0xffff0000u);
}

// ---------------------------------------------------------------------------
// prep (+ deg zero)
// ---------------------------------------------------------------------------
__global__ void prep_kernel(const float* __restrict__ Ws, const float* __restrict__ als,
                            const float* __restrict__ ars,
                            unsigned short* __restrict__ Wt,
                            unsigned short* __restrict__ combo, int* __restrict__ deg) {
    int b = blockIdx.x;
    if (b >= 288) {
        int idx = (b - 288) * 1024 + threadIdx.x * 4;
        if (idx < NDEG) *reinterpret_cast<int4*>(&deg[idx]) = int4{0, 0, 0, 0};
        return;
    }
    int idx = b * 256 + threadIdx.x;
    if (idx < 65536) {
        int r = idx >> 14, rem = idx & 16383, c = rem >> 7, k = rem & 127;
        Wt[idx] = f2bf(Ws[(r << 14) + k * 128 + c]);
    } else if (idx < 65536 + 8192) {
        int j = idx - 65536;
        int r = j >> 11, rem = j & 2047, n = rem >> 7, k = rem & 127;
        int p = r ^ 1;
        const float *W, *a;
        if (n < 8) {
            W = Ws + (r << 14) + k * 128 + n * 16;
            a = als + r * 128 + n * 16;
        } else {
            int h = n - 8;
            W = Ws + (p << 14) + k * 128 + h * 16;
            a = ars + p * 128 + h * 16;
        }
        float s = 0.f;
#pragma unroll
        for (int d = 0; d < 16; ++d) s += W[d] * a[d];
        combo[j] = f2bf(s);
    }
}

// ---------------------------------------------------------------------------
// CSR count (standalone, before the scans)
// ---------------------------------------------------------------------------
struct EdgePtrs {
    const int* esrc[4];
    const int* edst[4];
    int ebase[5];
    int nbase[4];
};

__global__ void csr_count(EdgePtrs cp, int* __restrict__ deg) {
    int idx = blockIdx.x * 256 + threadIdx.x;
    if (idx >= cp.ebase[4]) return;
    int r = 0;
    while (idx >= cp.ebase[r + 1]) ++r;
    atomicAdd(&deg[cp.nbase[r] + cp.edst[r][idx - cp.ebase[r]]], 1);
}

// ---------------------------------------------------------------------------
// scan
// ---------------------------------------------------------------------------
__global__ __launch_bounds__(256) void scan_bsum(const int* __restrict__ deg,
                                                 int* __restrict__ bsums, int N) {
    int base = blockIdx.x * 1024 + threadIdx.x * 4;
    int s = 0;
#pragma unroll
    for (int j = 0; j < 4; ++j) {
        int i = base + j;
        if (i < N) s += deg[i];
    }
#pragma unroll
    for (int off = 32; off; off >>= 1) s += __shfl_down(s, off);
    __shared__ int wt[4];
    if ((threadIdx.x & 63) == 0) wt[threadIdx.x >> 6] = s;
    __syncthreads();
    if (threadIdx.x == 0) bsums[blockIdx.x] = wt[0] + wt[1] + wt[2] + wt[3];
}

__global__ __launch_bounds__(256) void scan_final(const int* __restrict__ deg,
                                                  const int* __restrict__ bsums,
                                                  int* __restrict__ row_ptr,
                                                  int* __restrict__ cursor, int N) {
    int t = threadIdx.x;
    __shared__ int s_start;
    __shared__ int wsum[4];
    {
        int acc = 0;
        for (int i = t; i < (int)blockIdx.x; i += 256) acc += bsums[i];
#pragma unroll
        for (int off = 32; off; off >>= 1) acc += __shfl_down(acc, off);
        if ((t & 63) == 0) wsum[t >> 6] = acc;
        __syncthreads();
        if (t == 0) s_start = wsum[0] + wsum[1] + wsum[2] + wsum[3];
        __syncthreads();
    }
    int base = blockIdx.x * 1024 + t * 4;
    int d[4];
    int s = 0;
#pragma unroll
    for (int j = 0; j < 4; ++j) {
        int i = base + j;
        d[j] = (i < N) ? deg[i] : 0;
        s += d[j];
    }
    int inc = s;
#pragma unroll
    for (int off = 1; off < 64; off <<= 1) {
        int u = __shfl_up(inc, off);
        if ((t & 63) >= off) inc += u;
    }
    __shared__ int wt[4];
    if ((t & 63) == 63) wt[t >> 6] = inc;
    __syncthreads();
    int start = s_start;
    for (int w = 0; w < (t >> 6); ++w) start += wt[w];
    start += inc - s;
#pragma unroll
    for (int j = 0; j < 4; ++j) {
        int i = base + j;
        if (i < N) {
            row_ptr[i] = start;
            cursor[i] = start;
        }
        start += d[j];
    }
    if (base < N && base + 4 >= N) row_ptr[N] = start;
}

// ---------------------------------------------------------------------------
// Projection helpers (256 threads, 4 waves, 64 rows/block — R8-proven)
// ---------------------------------------------------------------------------
__device__ __forceinline__ void stage_W(unsigned short* Wl,
                                        const unsigned short* __restrict__ Wt,
                                        const unsigned short* __restrict__ cb, int tid) {
#pragma unroll
    for (int it = 0; it < 9; ++it) {
        int id = it * 256 + tid;
        int r = id >> 4, c8 = id & 15;
        const unsigned short* srcp = (r < 128) ? (Wt + r * 128) : (cb + (r - 128) * 128);
        uint4 v = *reinterpret_cast<const uint4*>(srcp + c8 * 8);
        *reinterpret_cast<uint4*>(&Wl[(r * 16 + (c8 ^ (r & 15))) * 8]) = v;
    }
}

__device__ __forceinline__ void mfma_set(const unsigned short* Wl, unsigned short* Abf,
                                         const bf16x8* af, int tid, int row0, int N,
                                         float* __restrict__ el, float* __restrict__ er) {
    const int l = tid & 63, w = tid >> 6, lrow = l & 15, lk8 = l >> 4;
#pragma unroll
    for (int t9 = 0; t9 < 9; ++t9) {
        f32x4 acc = f32x4{0.f, 0.f, 0.f, 0.f};
#pragma unroll
        for (int ks = 0; ks < 4; ++ks) {
            int wrow = t9 * 16 + lrow;
            int c8 = ks * 4 + lk8;
            bf16x8 bf = *reinterpret_cast<const bf16x8*>(
                &Wl[(wrow * 16 + (c8 ^ (wrow & 15))) * 8]);
            acc = __builtin_amdgcn_mfma_f32_16x16x32_bf16(af[ks], bf, acc, 0, 0, 0);
        }
        if (t9 < 8) {
#pragma unroll
            for (int r = 0; r < 4; ++r) {
                int rl = w * 16 + lk8 * 4 + r;
                int col = t9 * 16 + lrow;
                Abf[(rl * 16 + ((col >> 3) ^ (rl & 15))) * 8 + (col & 7)] = f2bf(acc[r]);
            }
        } else {
#pragma unroll
            for (int r = 0; r < 4; ++r) {
                int row = row0 + w * 16 + lk8 * 4 + r;
                if (row < N) {
                    if (lrow < 8) el[(size_t)row * 8 + lrow] = acc[r];
                    else er[(size_t)row * 8 + (lrow - 8)] = acc[r];
                }
            }
        }
    }
}

__device__ __forceinline__ void store_hs(const unsigned short* Abf,
                                         unsigned short* __restrict__ hs, int tid,
                                         int row0, int N) {
#pragma unroll
    for (int it = 0; it < 4; ++it) {
        int id = it * 256 + tid;
        int r = id >> 4, c8 = id & 15;
        int row = row0 + r;
        if (row < N) {
            uint4 v = *reinterpret_cast<const uint4*>(&Abf[(r * 16 + (c8 ^ (r & 15))) * 8]);
            *reinterpret_cast<uint4*>(hs + (size_t)row * 128 + c8 * 8) = v;
        }
    }
}

// ---------------------------------------------------------------------------
// Fused CSR-scatter + projection (R8 projection body, scatter blocks lead).
// ---------------------------------------------------------------------------
struct SPArgs {
    const int* esrc[4];
    const int* edst[4];
    int ebase[5];
    int nbase[4];
    int* cursor;
    int* scsr;
    int sblk;
    const float* A[6];
    int N[6];
    int blk0[7];
    const unsigned short* Wt1[6];
    const unsigned short* cb1[6];
    unsigned short* hs1[6];
    float* el1[6];
    float* er1[6];
    const unsigned short* Wt2[6];
    const unsigned short* cb2[6];
    unsigned short* hs2[6];
    float* el2[6];
    float* er2[6];
    int has2[6];
};

__global__ __launch_bounds__(256) void scatter_project(SPArgs a) {
    __shared__ unsigned short Abf[64 * 128];   // 16 KiB
    __shared__ unsigned short Wl[144 * 128];   // 36 KiB
    int bb = blockIdx.x;
    const int tid = threadIdx.x;
    if (bb < a.sblk) {
        int idx = bb * 256 + tid;
        if (idx < a.ebase[4]) {
            int r = 0;
            while (idx >= a.ebase[r + 1]) ++r;
            int e = idx - a.ebase[r];
            int p = atomicAdd(&a.cursor[a.nbase[r] + a.edst[r][e]], 1);
            a.scsr[p] = a.esrc[r][e];
        }
        return;
    }
    bb -= a.sblk;
    int t = 0;
    while (bb >= a.blk0[t + 1]) ++t;
    const int row0 = (bb - a.blk0[t]) * 64;
    const int N = a.N[t];
    const float* A = a.A[t];

    // stage A (f32 -> bf16, swizzled; nontemporal read-once) + stage W1
#pragma unroll
    for (int it = 0; it < 4; ++it) {
        int id = it * 256 + tid;
        int r = id >> 4, c8 = id & 15;
        int row = row0 + r;
        if (row >= N) row = N - 1;
        const f32x4* ap = reinterpret_cast<const f32x4*>(A + (size_t)row * 128 + c8 * 8);
        f32x4 v0 = __builtin_nontemporal_load(ap);
        f32x4 v1 = __builtin_nontemporal_load(ap + 1);
        uint4 pk;
        pk.x = (unsigned)f2bf(v0.x) | ((unsigned)f2bf(v0.y) << 16);
        pk.y = (unsigned)f2bf(v0.z) | ((unsigned)f2bf(v0.w) << 16);
        pk.z = (unsigned)f2bf(v1.x) | ((unsigned)f2bf(v1.y) << 16);
        pk.w = (unsigned)f2bf(v1.z) | ((unsigned)f2bf(v1.w) << 16);
        *reinterpret_cast<uint4*>(&Abf[(r * 16 + (c8 ^ (r & 15))) * 8]) = pk;
    }
    stage_W(Wl, a.Wt1[t], a.cb1[t], tid);
    __syncthreads();

    const int l = tid & 63, w = tid >> 6, lrow = l & 15, lk8 = l >> 4;
    bf16x8 af[4];
    const int arow = w * 16 + lrow;
#pragma unroll
    for (int ks = 0; ks < 4; ++ks) {
        int c8 = ks * 4 + lk8;
        af[ks] = *reinterpret_cast<const bf16x8*>(
            &Abf[(arow * 16 + (c8 ^ (arow & 15))) * 8]);
    }
    __syncthreads();  // Abf now reusable as D staging

    mfma_set(Wl, Abf, af, tid, row0, N, a.el1[t], a.er1[t]);
    __syncthreads();
    store_hs(Abf, a.hs1[t], tid, row0, N);
    if (!a.has2[t]) return;
    stage_W(Wl, a.Wt2[t], a.cb2[t], tid);  // disjoint LDS from store_hs reads
    __syncthreads();
    mfma_set(Wl, Abf, af, tid, row0, N, a.el2[t], a.er2[t]);
    __syncthreads();
    store_hs(Abf, a.hs2[t], tid, row0, N);
}

// ---------------------------------------------------------------------------
// Dual-input edge-list accumulate (16-lane group, 4-edge unroll)
// ---------------------------------------------------------------------------
__device__ __forceinline__ void acc_dual(
    int p0, int p1, float erd0, float erd1, int l, int h,
    const int* __restrict__ srcs,
    const float* __restrict__ el0, const float* __restrict__ el1,
    const unsigned short* __restrict__ hs0, const unsigned short* __restrict__ hs1,
    float* A0, float* A1, float& DS0, float& DS1) {
    float a0[8], a1[8];
#pragma unroll
    for (int j = 0; j < 8; ++j) { a0[j] = 0.f; a1[j] = 0.f; }
    float d0 = 0.f, d1 = 0.f;
    int p = p0;
    for (; p + 4 <= p1; p += 4) {
        int sx[4];
#pragma unroll
        for (int u = 0; u < 4; ++u) sx[u] = srcs[p + u];
        float ev0[4], ev1[4];
        uint4 q0[4], q1[4];
#pragma unroll
        for (int u = 0; u < 4; ++u) {
            ev0[u] = el0[(size_t)sx[u] * 8 + h] + erd0;
            ev1[u] = el1[(size_t)sx[u] * 8 + h] + erd1;
            q0[u] = *reinterpret_cast<const uint4*>(hs0 + (size_t)sx[u] * 128 + l * 8);
            q1[u] = *reinterpret_cast<const uint4*>(hs1 + (size_t)sx[u] * 128 + l * 8);
        }
#pragma unroll
        for (int u = 0; u < 4; ++u) {
            float e0 = ev0[u];
            e0 = e0 > 0.f ? e0 : 0.2f * e0;
            float ee0 = __expf(e0);
            d0 += ee0;
            a0[0] += ee0 * bf2f_lo(q0[u].x);
            a0[1] += ee0 * bf2f_hi(q0[u].x);
            a0[2] += ee0 * bf2f_lo(q0[u].y);
            a0[3] += ee0 * bf2f_hi(q0[u].y);
            a0[4] += ee0 * bf2f_lo(q0[u].z);
            a0[5] += ee0 * bf2f_hi(q0[u].z);
            a0[6] += ee0 * bf2f_lo(q0[u].w);
            a0[7] += ee0 * bf2f_hi(q0[u].w);
            float e1 = ev1[u];
            e1 = e1 > 0.f ? e1 : 0.2f * e1;
            float ee1 = __expf(e1);
            d1 += ee1;
            a1[0] += ee1 * bf2f_lo(q1[u].x);
            a1[1] += ee1 * bf2f_hi(q1[u].x);
            a1[2] += ee1 * bf2f_lo(q1[u].y);
            a1[3] += ee1 * bf2f_hi(q1[u].y);
            a1[4] += ee1 * bf2f_lo(q1[u].z);
            a1[5] += ee1 * bf2f_hi(q1[u].z);
            a1[6] += ee1 * bf2f_lo(q1[u].w);
            a1[7] += ee1 * bf2f_hi(q1[u].w);
        }
    }
    for (; p < p1; ++p) {
        int s = srcs[p];
        float e0 = el0[(size_t)s * 8 + h] + erd0;
        float e1 = el1[(size_t)s * 8 + h] + erd1;
        uint4 q0 = *reinterpret_cast<const uint4*>(hs0 + (size_t)s * 128 + l * 8);
        uint4 q1 = *reinterpret_cast<const uint4*>(hs1 + (size_t)s * 128 + l * 8);
        e0 = e0 > 0.f ? e0 : 0.2f * e0;
        float ee0 = __expf(e0);
        d0 += ee0;
        a0[0] += ee0 * bf2f_lo(q0.x);
        a0[1] += ee0 * bf2f_hi(q0.x);
        a0[2] += ee0 * bf2f_lo(q0.y);
        a0[3] += ee0 * bf2f_hi(q0.y);
        a0[4] += ee0 * bf2f_lo(q0.z);
        a0[5] += ee0 * bf2f_hi(q0.z);
        a0[6] += ee0 * bf2f_lo(q0.w);
        a0[7] += ee0 * bf2f_hi(q0.w);
        e1 = e1 > 0.f ? e1 : 0.2f * e1;
        float ee1 = __expf(e1);
        d1 += ee1;
        a1[0] += ee1 * bf2f_lo(q1.x);
        a1[1] += ee1 * bf2f_hi(q1.x);
        a1[2] += ee1 * bf2f_lo(q1.y);
        a1[3] += ee1 * bf2f_hi(q1.y);
        a1[4] += ee1 * bf2f_lo(q1.z);
        a1[5] += ee1 * bf2f_hi(q1.z);
        a1[6] += ee1 * bf2f_lo(q1.w);
        a1[7] += ee1 * bf2f_hi(q1.w);
    }
#pragma unroll
    for (int j = 0; j < 8; ++j) { A0[j] = a0[j]; A1[j] = a1[j]; }
    DS0 = d0;
    DS1 = d1;
}

__device__ __forceinline__ void nt_store2(float* op, f32x4 o0, f32x4 o1) {
    f32x4* vp = reinterpret_cast<f32x4*>(op);
    __builtin_nontemporal_store(o0, vp);
    __builtin_nontemporal_store(o1, vp + 1);
}

// ---------------------------------------------------------------------------
// Mega aggregation, dual-input groups.
// ---------------------------------------------------------------------------
#define PB2 6250
#define AB2 3750
#define SB2 1000

struct AggArgs {
    const int* rp;
    const int* srcs;
    const float* el[8];              // [inp*4 + rel]
    const float* er[8];
    const unsigned short* hs[8];
    const float* bs;                 // 4 x 128
    float* out0;
    float* out1;
};

__global__ __launch_bounds__(256) void mega_agg(AggArgs a) {
    int blk = blockIdx.x;
    __shared__ float Am[16][128];
    __shared__ float Dm[16][8];

    if (blk < PB2) {
        int dst = blk * 16 + (threadIdx.x >> 4);
        int l = threadIdx.x & 15, h = l >> 1;
        if (dst >= NPAPER) return;
        float A1_0[8], A1_1[8], d1_0, d1_1;
        acc_dual(a.rp[60000 + dst], a.rp[60000 + dst + 1],
                 a.er[1][(size_t)dst * 8 + h], a.er[5][(size_t)dst * 8 + h], l, h,
                 a.srcs, a.el[1], a.el[5], a.hs[1], a.hs[5], A1_0, A1_1, d1_0, d1_1);
        float A3_0[8], A3_1[8], d3_0, d3_1;
        acc_dual(a.rp[161000 + dst], a.rp[161000 + dst + 1],
                 a.er[3][(size_t)dst * 8 + h], a.er[7][(size_t)dst * 8 + h], l, h,
                 a.srcs, a.el[3], a.el[7], a.hs[3], a.hs[7], A3_0, A3_1, d3_0, d3_1);
        const float4* bp1 = reinterpret_cast<const float4*>(a.bs + 128 + l * 8);
        const float4* bp3 = reinterpret_cast<const float4*>(a.bs + 384 + l * 8);
        float4 b10 = bp1[0], b11 = bp1[1], b30 = bp3[0], b31 = bp3[1];
        float i1 = 1.f / fmaxf(d1_0, 1e-9f);
        float i3 = 1.f / fmaxf(d3_0, 1e-9f);
        f32x4 o0, o1;
        o0.x = 0.5f * ((A1_0[0] * i1 + b10.x) + (A3_0[0] * i3 + b30.x));
        o0.y = 0.5f * ((A1_0[1] * i1 + b10.y) + (A3_0[1] * i3 + b30.y));
        o0.z = 0.5f * ((A1_0[2] * i1 + b10.z) + (A3_0[2] * i3 + b30.z));
        o0.w = 0.5f * ((A1_0[3] * i1 + b10.w) + (A3_0[3] * i3 + b30.w));
        o1.x = 0.5f * ((A1_0[4] * i1 + b11.x) + (A3_0[4] * i3 + b31.x));
        o1.y = 0.5f * ((A1_0[5] * i1 + b11.y) + (A3_0[5] * i3 + b31.y));
        o1.z = 0.5f * ((A1_0[6] * i1 + b11.z) + (A3_0[6] * i3 + b31.z));
        o1.w = 0.5f * ((A1_0[7] * i1 + b11.w) + (A3_0[7] * i3 + b31.w));
        nt_store2(a.out0 + (size_t)dst * 128 + l * 8, o0, o1);
        i1 = 1.f / fmaxf(d1_1, 1e-9f);
        i3 = 1.f / fmaxf(d3_1, 1e-9f);
        o0.x = 0.5f * ((A1_1[0] * i1 + b10.x) + (A3_1[0] * i3 + b30.x));
        o0.y = 0.5f * ((A1_1[1] * i1 + b10.y) + (A3_1[1] * i3 + b30.y));
        o0.z = 0.5f * ((A1_1[2] * i1 + b10.z) + (A3_1[2] * i3 + b30.z));
        o0.w = 0.5f * ((A1_1[3] * i1 + b10.w) + (A3_1[3] * i3 + b30.w));
        o1.x = 0.5f * ((A1_1[4] * i1 + b11.x) + (A3_1[4] * i3 + b31.x));
        o1.y = 0.5f * ((A1_1[5] * i1 + b11.y) + (A3_1[5] * i3 + b31.y));
        o1.z = 0.5f * ((A1_1[6] * i1 + b11.z) + (A3_1[6] * i3 + b31.z));
        o1.w = 0.5f * ((A1_1[7] * i1 + b11.w) + (A3_1[7] * i3 + b31.w));
        nt_store2(a.out1 + (size_t)dst * 128 + l * 8, o0, o1);
    } else if (blk < PB2 + AB2) {
        int dst = (blk - PB2) * 16 + (threadIdx.x >> 4);
        int l = threadIdx.x & 15, h = l >> 1;
        if (dst >= NAUTHOR) return;
        float A0[8], A1[8], d0, d1;
        acc_dual(a.rp[dst], a.rp[dst + 1],
                 a.er[0][(size_t)dst * 8 + h], a.er[4][(size_t)dst * 8 + h], l, h,
                 a.srcs, a.el[0], a.el[4], a.hs[0], a.hs[4], A0, A1, d0, d1);
        const float4* bp = reinterpret_cast<const float4*>(a.bs + l * 8);
        float4 b0 = bp[0], b1 = bp[1];
        float inv = 1.f / fmaxf(d0, 1e-9f);
        f32x4 o0 = {A0[0] * inv + b0.x, A0[1] * inv + b0.y,
                    A0[2] * inv + b0.z, A0[3] * inv + b0.w};
        f32x4 o1 = {A0[4] * inv + b1.x, A0[5] * inv + b1.y,
                    A0[6] * inv + b1.z, A0[7] * inv + b1.w};
        nt_store2(a.out0 + (size_t)(NPAPER + dst) * 128 + l * 8, o0, o1);
        inv = 1.f / fmaxf(d1, 1e-9f);
        o0 = f32x4{A1[0] * inv + b0.x, A1[1] * inv + b0.y,
                   A1[2] * inv + b0.z, A1[3] * inv + b0.w};
        o1 = f32x4{A1[4] * inv + b1.x, A1[5] * inv + b1.y,
                   A1[6] * inv + b1.z, A1[7] * inv + b1.w};
        nt_store2(a.out1 + (size_t)(NPAPER + dst) * 128 + l * 8, o0, o1);
    } else {
        int dst = blk - (PB2 + AB2);
        int gl = threadIdx.x >> 4;
        int inp = gl >> 3, ck = gl & 7;
        int l = threadIdx.x & 15, h = l >> 1;
        const float* el = a.el[inp * 4 + 2];
        const float* er = a.er[inp * 4 + 2];
        const unsigned short* hs = a.hs[inp * 4 + 2];
        int p0 = a.rp[160000 + dst], p1 = a.rp[160000 + dst + 1];
        float erd = er[(size_t)dst * 8 + h];
        float acc8[8];
#pragma unroll
        for (int j = 0; j < 8; ++j) acc8[j] = 0.f;
        float dsum = 0.f;
        for (int p = p0 + ck; p < p1; p += 8) {
            int s = a.srcs[p];
            float e = el[(size_t)s * 8 + h] + erd;
            e = e > 0.f ? e : 0.2f * e;
            float ee = __expf(e);
            uint4 q = *reinterpret_cast<const uint4*>(hs + (size_t)s * 128 + l * 8);
            dsum += ee;
            acc8[0] += ee * bf2f_lo(q.x);
            acc8[1] += ee * bf2f_hi(q.x);
            acc8[2] += ee * bf2f_lo(q.y);
            acc8[3] += ee * bf2f_hi(q.y);
            acc8[4] += ee * bf2f_lo(q.z);
            acc8[5] += ee * bf2f_hi(q.z);
            acc8[6] += ee * bf2f_lo(q.w);
            acc8[7] += ee * bf2f_hi(q.w);
        }
#pragma unroll
        for (int j = 0; j < 8; ++j) Am[gl][l * 8 + j] = acc8[j];
        if ((l & 1) == 0) Dm[gl][h] = dsum;
        __syncthreads();
        int c = threadIdx.x;
        int ci = c >> 7;
        int col = c & 127;
        float s = 0.f, dn = 0.f;
        int hh = col >> 4;
#pragma unroll
        for (int g = 0; g < 8; ++g) {
            s += Am[ci * 8 + g][col];
            dn += Dm[ci * 8 + g][hh];
        }
        float v = s / fmaxf(dn, 1e-9f) + a.bs[256 + col];
        float* outp = (ci ? a.out1 : a.out0) + (size_t)(NPAPER + NAUTHOR + dst) * 128 + col;
        __builtin_nontemporal_store(v, outp);
    }
}

// ---------------------------------------------------------------------------
extern "C" void kernel_launch(void* const* d_in, const int* in_sizes, int n_in,
                              void* d_out, int out_size, void* d_ws, size_t ws_size,
                              hipStream_t stream) {
    const float* Ws4 = (const float*)d_in[14];
    const float* als = (const float*)d_in[15];
    const float* ars = (const float*)d_in[16];
    const float* bs = (const float*)d_in[17];
    float* out = (float*)d_out;

    const int Es[4] = {in_sizes[6], in_sizes[8], in_sizes[10], in_sizes[12]};
    const int Nsrcs[4] = {NPAPER, NAUTHOR, NPAPER, NSUBJ};
    const int Ndsts[4] = {NAUTHOR, NPAPER, NSUBJ, NPAPER};
    const int Etot = Es[0] + Es[1] + Es[2] + Es[3];

    char* wsp = (char*)d_ws;
    auto carve = [&](size_t bytes) {
        char* p = wsp;
        wsp += (bytes + 255) & ~(size_t)255;
        return p;
    };
    unsigned short* Wt = (unsigned short*)carve(4 * 16384 * 2);
    unsigned short* combo = (unsigned short*)carve(4 * 2048 * 2);
    unsigned short* hsb[2][4];
    float* elb[2][4];
    float* erb[2][4];
    for (int i = 0; i < 2; ++i)
        for (int r = 0; r < 4; ++r) {
            hsb[i][r] = (unsigned short*)carve((size_t)Nsrcs[r] * 128 * 2);
            elb[i][r] = (float*)carve((size_t)Nsrcs[r] * 8 * 4);
            erb[i][r] = (float*)carve((size_t)Ndsts[r] * 8 * 4);
        }
    int* deg = (int*)carve((size_t)NDEG * 4);
    int* cursor = (int*)carve((size_t)NDEG * 4);
    int* bsums = (int*)carve(1024);
    int* rp = (int*)carve((size_t)(NDEG + 1) * 4);
    int* scsr = (int*)carve((size_t)Etot * 4);

    EdgePtrs ep;
    ep.esrc[0] = (const int*)d_in[6];  ep.edst[0] = (const int*)d_in[7];
    ep.esrc[1] = (const int*)d_in[8];  ep.edst[1] = (const int*)d_in[9];
    ep.esrc[2] = (const int*)d_in[10]; ep.edst[2] = (const int*)d_in[11];
    ep.esrc[3] = (const int*)d_in[12]; ep.edst[3] = (const int*)d_in[13];
    ep.ebase[0] = 0;
    for (int r = 0; r < 4; ++r) ep.ebase[r + 1] = ep.ebase[r] + Es[r];
    ep.nbase[0] = 0;
    ep.nbase[1] = 60000;
    ep.nbase[2] = 160000;
    ep.nbase[3] = 161000;

    // 1. prep (Wt/combo) + deg zero
    prep_kernel<<<288 + (NDEG + 1023) / 1024, 256, 0, stream>>>(Ws4, als, ars, Wt,
                                                                combo, deg);
    // 2. count
    csr_count<<<(Etot + 255) / 256, 256, 0, stream>>>(ep, deg);
    // 3-4. scan
    int nb = (NDEG + 1023) / 1024;  // 255
    scan_bsum<<<nb, 256, 0, stream>>>(deg, bsums, NDEG);
    scan_final<<<nb, 256, 0, stream>>>(deg, bsums, rp, cursor, NDEG);

    // 5. scatter (leading blocks) + projection (R8 body, 256 threads)
    SPArgs sp;
    for (int r = 0; r < 4; ++r) {
        sp.esrc[r] = ep.esrc[r];
        sp.edst[r] = ep.edst[r];
        sp.nbase[r] = ep.nbase[r];
    }
    for (int r = 0; r < 5; ++r) sp.ebase[r] = ep.ebase[r];
    sp.cursor = cursor;
    sp.scsr = scsr;
    sp.sblk = (Etot + 255) / 256;

    int blk = 0;
    for (int ti = 0; ti < 6; ++ti) {
        int i = ti & 1;
        int nodeT = ti >> 1;  // 0 paper, 1 author, 2 subject
        const int relOf[3] = {0, 1, 3};
        int r = relOf[nodeT];
        const float* feats[3] = {(const float*)d_in[0 + 3 * i],
                                 (const float*)d_in[1 + 3 * i],
                                 (const float*)d_in[2 + 3 * i]};
        sp.A[ti] = feats[nodeT];
        sp.N[ti] = (nodeT == 0) ? NPAPER : (nodeT == 1 ? NAUTHOR : NSUBJ);
        sp.blk0[ti] = blk;
        blk += (sp.N[ti] + 63) / 64;
        sp.Wt1[ti] = Wt + (size_t)r * 16384;
        sp.cb1[ti] = combo + (size_t)r * 2048;
        sp.hs1[ti] = hsb[i][r];
        sp.el1[ti] = elb[i][r];
        sp.er1[ti] = erb[i][r ^ 1];
        sp.has2[ti] = (nodeT == 0);
        int r2 = 2;
        sp.Wt2[ti] = Wt + (size_t)r2 * 16384;
        sp.cb2[ti] = combo + (size_t)r2 * 2048;
        sp.hs2[ti] = hsb[i][r2];
        sp.el2[ti] = elb[i][r2];
        sp.er2[ti] = erb[i][r2 ^ 1];
    }
    sp.blk0[6] = blk;
    scatter_project<<<sp.sblk + blk, 256, 0, stream>>>(sp);

    // 6. mega aggregation (dual-input groups)
    AggArgs ag;
    ag.rp = rp;
    ag.srcs = scsr;
    for (int i = 0; i < 2; ++i)
        for (int r = 0; r < 4; ++r) {
            ag.el[i * 4 + r] = elb[i][r];
            ag.er[i * 4 + r] = erb[i][r];
            ag.hs[i * 4 + r] = hsb[i][r];
        }
    ag.bs = bs;
    ag.out0 = out;
    ag.out1 = out + (size_t)NTOT * 128;
    mega_agg<<<PB2 + AB2 + SB2, 256, 0, stream>>>(ag);
}